// Round 7
// baseline (383.019 us; speedup 1.0000x reference)
//
#include <hip/hip_runtime.h>

static constexpr int Bc = 4, Tc = 1024, Sc = 1024, Dc = 1024, Hc = 16, DHc = 64, FFc = 4096;

typedef __attribute__((ext_vector_type(8))) short short8;
typedef __attribute__((ext_vector_type(4))) short short4v;
typedef __attribute__((ext_vector_type(4))) float f32x4;

__device__ __forceinline__ unsigned short f2bf(float f) {
    unsigned int u = __float_as_uint(f);
    unsigned int r = u + 0x7fffu + ((u >> 16) & 1u);
    return (unsigned short)(r >> 16);
}
__device__ __forceinline__ float bf2f(unsigned short u) {
    return __uint_as_float(((unsigned int)u) << 16);
}

__device__ __forceinline__ void gload_lds16(const void* g, void* l) {
    __builtin_amdgcn_global_load_lds((const __attribute__((address_space(1))) void*)g,
                                     (__attribute__((address_space(3))) void*)l, 16, 0, 0);
}

// ---------------- cast f32 -> bf16 ----------------
__global__ __launch_bounds__(256) void cast_f32_bf16(const float* __restrict__ in,
                                                     unsigned short* __restrict__ out, int n8) {
    int i = blockIdx.x * 256 + threadIdx.x;
    if (i >= n8) return;
    const float4* p = (const float4*)in + (size_t)i * 2;
    float4 a = p[0], b = p[1];
    short8 o;
    o[0] = f2bf(a.x); o[1] = f2bf(a.y); o[2] = f2bf(a.z); o[3] = f2bf(a.w);
    o[4] = f2bf(b.x); o[5] = f2bf(b.y); o[6] = f2bf(b.z); o[7] = f2bf(b.w);
    *(short8*)(out + (size_t)i * 8) = o;
}

// ---------------- transpose + cast: W(K,N) f32 -> Wt(N,K) bf16 ----------------
__global__ __launch_bounds__(256) void transpose_cast(const float* __restrict__ W,
                                                      unsigned short* __restrict__ Wt,
                                                      int K, int N) {
    __shared__ float tile[32][33];
    int n0 = blockIdx.x * 32, k0 = blockIdx.y * 32;
    int tx = threadIdx.x, ty = threadIdx.y;  // (32,8)
#pragma unroll
    for (int i = 0; i < 4; i++)
        tile[ty + i * 8][tx] = W[(size_t)(k0 + ty + i * 8) * N + n0 + tx];
    __syncthreads();
#pragma unroll
    for (int i = 0; i < 4; i++)
        Wt[(size_t)(n0 + ty + i * 8) * K + k0 + tx] = f2bf(tile[tx][ty + i * 8]);
}

// batched version for 8 square 1024x1024 weights
struct TP8 { const float* s[8]; unsigned short* d[8]; };
__global__ __launch_bounds__(256) void transpose_cast8(TP8 p) {
    __shared__ float tile[32][33];
    const float* W = p.s[blockIdx.z];
    unsigned short* Wt = p.d[blockIdx.z];
    int n0 = blockIdx.x * 32, k0 = blockIdx.y * 32;
    int tx = threadIdx.x, ty = threadIdx.y;
#pragma unroll
    for (int i = 0; i < 4; i++)
        tile[ty + i * 8][tx] = W[(size_t)(k0 + ty + i * 8) * 1024 + n0 + tx];
    __syncthreads();
#pragma unroll
    for (int i = 0; i < 4; i++)
        Wt[(size_t)(n0 + ty + i * 8) * 1024 + k0 + tx] = f2bf(tile[tx][ty + i * 8]);
}

// ---------------- concat biases (1024-elem segments) ----------------
__global__ void concat_bias(const float* b0, const float* b1, const float* b2,
                            float* __restrict__ out) {
    int i = blockIdx.x * 256 + threadIdx.x;
    int seg = i >> 10, j = i & 1023;
    const float* p = seg == 0 ? b0 : (seg == 1 ? b1 : b2);
    out[i] = p[j];
}

// ---------------- per-head V transpose ----------------
__global__ __launch_bounds__(256) void transpose_v(const unsigned short* __restrict__ V, int ldv,
                                                   unsigned short* __restrict__ Vt) {
    __shared__ unsigned short t[64 * 64];
    const int bh = blockIdx.y, b = bh >> 4, h = bh & 15;
    const int s0 = blockIdx.x * 64;
    const int tid = threadIdx.x;
    const int r = tid >> 2, ch = tid & 3;
    const unsigned short* src = V + (size_t)(b * 1024 + s0 + r) * ldv + h * 64 + ch * 16;
    short8 v0 = *(const short8*)src;
    short8 v1 = *(const short8*)(src + 8);
    int pw_ = (ch ^ r ^ (r >> 4)) & 3;
    *(short8*)(t + r * 64 + pw_ * 16) = v0;
    *(short8*)(t + r * 64 + pw_ * 16 + 8) = v1;
    __syncthreads();
    const int dh = tid >> 2, sc = (tid & 3) * 16;
    short8 o0, o1;
#pragma unroll
    for (int j = 0; j < 8; j++) {
        int c0 = sc + j, c1 = sc + 8 + j;
        o0[j] = t[c0 * 64 + (((dh >> 4) ^ c0 ^ (c0 >> 4)) & 3) * 16 + (dh & 15)];
        o1[j] = t[c1 * 64 + (((dh >> 4) ^ c1 ^ (c1 >> 4)) & 3) * 16 + (dh & 15)];
    }
    unsigned short* dst = Vt + ((size_t)bh * 64 + dh) * 1024 + s0 + sc;
    *(short8*)dst = o0;
    *(short8*)(dst + 8) = o1;
}

// ---- block remap: chunked-XCD + group-major(8) rasterization (bijective, nwg%8==0) ----
struct BlkMap { int m, n, z; };
__device__ __forceinline__ BlkMap remap_block() {
    const int gx = gridDim.x, gy = gridDim.y;
    const int nxy = gx * gy;
    const int nwg = nxy * gridDim.z;
    const int flat = (blockIdx.z * gy + blockIdx.y) * gx + blockIdx.x;
    const int id = (flat & 7) * (nwg >> 3) + (flat >> 3);
    const int pz = id / nxy;
    const int rz = id - pz * nxy;
    const int gsz = 8 * gy;
    const int grp = rz / gsz;
    const int rem = rz - grp * gsz;
    BlkMap r;
    r.m = rem >> 3;
    r.n = grp * 8 + (rem & 7);
    r.z = pz;
    return r;
}

// ---------------- GEMM 128x128: 4-buffer LDS depth-3 prefetch, counted vmcnt, XCD-swizzled ----
// EPI: 0 = bf16, 1 = f32 (split-K partial, out += z*M*N, bias only z==0), 2 = relu+bf16
template <int EPI>
__global__ __launch_bounds__(256) void gemm_db(const unsigned short* __restrict__ A,
                                               const unsigned short* __restrict__ Bt,
                                               const float* __restrict__ bias,
                                               float* __restrict__ outF,
                                               unsigned short* __restrict__ outB,
                                               int M, int N, int Kloop, int lda, int ldb) {
    __shared__ unsigned short As[4][128 * 32];
    __shared__ unsigned short Bs[4][128 * 32];
    const int tid = threadIdx.x;
    const int w = tid >> 6, lane = tid & 63, l4 = lane & 15, g = lane >> 4;
    BlkMap bm = remap_block();
    const int m0 = bm.m * 128, n0 = bm.n * 128, z = bm.z;
    A += (size_t)z * Kloop;
    Bt += (size_t)z * Kloop;
    const int wr = w >> 1, wc = w & 1;
    f32x4 acc[4][4] = {};
    const int r0 = tid >> 2;
    const int kk = ((tid & 3) ^ ((tid >> 3) & 3)) * 8;   // pre-swizzled global source chunk
    const int sk = (l4 >> 1) & 3;                        // read-side swizzle key
    const unsigned short* Ar0 = A + (size_t)(m0 + r0) * lda + kk;
    const unsigned short* Ar1 = A + (size_t)(m0 + 64 + r0) * lda + kk;
    const unsigned short* Br0 = Bt + (size_t)(n0 + r0) * ldb + kk;
    const unsigned short* Br1 = Bt + (size_t)(n0 + 64 + r0) * ldb + kk;
    auto stage = [&](int sb, int k0) {
        gload_lds16(Ar0 + k0, (char*)As[sb] + tid * 16);
        gload_lds16(Ar1 + k0, (char*)As[sb] + 4096 + tid * 16);
        gload_lds16(Br0 + k0, (char*)Bs[sb] + tid * 16);
        gload_lds16(Br1 + k0, (char*)Bs[sb] + 4096 + tid * 16);
    };
    const int nk = Kloop >> 5;
    stage(0, 0);
    if (nk > 1) stage(1, 32);
    if (nk > 2) stage(2, 64);
    asm volatile("s_waitcnt vmcnt(8)" ::: "memory");   // tile 0 resident; 1,2 in flight
    __builtin_amdgcn_s_barrier();
    asm volatile("" ::: "memory");
    int buf = 0;
    for (int t = 0; t < nk; ++t) {
        if (t + 3 < nk) stage((buf + 3) & 3, (t + 3) * 32);
        short8 a[4], b[4];
#pragma unroll
        for (int m = 0; m < 4; m++)
            a[m] = *(const short8*)(As[buf] + (wr * 64 + m * 16 + l4) * 32 + (g ^ sk) * 8);
#pragma unroll
        for (int n = 0; n < 4; n++)
            b[n] = *(const short8*)(Bs[buf] + (wc * 64 + n * 16 + l4) * 32 + (g ^ sk) * 8);
#pragma unroll
        for (int m = 0; m < 4; m++)
#pragma unroll
            for (int n = 0; n < 4; n++)
                acc[m][n] = __builtin_amdgcn_mfma_f32_16x16x32_bf16(a[m], b[n], acc[m][n], 0, 0, 0);
        if (t + 1 < nk) {
            // certify tile t+1 only: N = 4 x (tiles staged beyond t+1)
            if (t + 3 < nk)      asm volatile("s_waitcnt vmcnt(8)" ::: "memory");
            else if (t + 2 < nk) asm volatile("s_waitcnt vmcnt(4)" ::: "memory");
            else                 asm volatile("s_waitcnt vmcnt(0)" ::: "memory");
            __builtin_amdgcn_s_barrier();
            asm volatile("" ::: "memory");
        }
        buf = (buf + 1) & 3;
    }
    const int rowB = m0 + wr * 64 + g * 4;
    const int colB = n0 + wc * 64 + l4;
    float* oF = (EPI == 1) ? outF + (size_t)z * M * N : outF;
#pragma unroll
    for (int n = 0; n < 4; n++) {
        float bv = (EPI == 1 && z != 0) ? 0.f : bias[colB + n * 16];
#pragma unroll
        for (int m = 0; m < 4; m++) {
#pragma unroll
            for (int r = 0; r < 4; r++) {
                float v = acc[m][n][r] + bv;
                if (EPI == 2) v = fmaxf(v, 0.f);
                size_t idx = (size_t)(rowB + m * 16 + r) * N + colB + n * 16;
                if (EPI == 1) oF[idx] = v;
                else outB[idx] = f2bf(v);
            }
        }
    }
}

// ---------------- GEMM 64x128: 4-buffer depth-3, counted vmcnt, XCD-swizzled ----------------
template <int EPI>
__global__ __launch_bounds__(256) void gemm64_db(const unsigned short* __restrict__ A,
                                                 const unsigned short* __restrict__ Bt,
                                                 const float* __restrict__ bias,
                                                 float* __restrict__ outF,
                                                 unsigned short* __restrict__ outB,
                                                 int M, int N, int Kloop, int lda, int ldb) {
    __shared__ unsigned short As[4][64 * 32];
    __shared__ unsigned short Bs[4][128 * 32];
    const int tid = threadIdx.x;
    const int w = tid >> 6, lane = tid & 63, l4 = lane & 15, g = lane >> 4;
    BlkMap bm = remap_block();
    const int m0 = bm.m * 64, n0 = bm.n * 128;
    f32x4 acc[4][2] = {};
    const int r0 = tid >> 2;
    const int kk = ((tid & 3) ^ ((tid >> 3) & 3)) * 8;
    const int sk = (l4 >> 1) & 3;
    const unsigned short* Ar0 = A + (size_t)(m0 + r0) * lda + kk;
    const unsigned short* Br0 = Bt + (size_t)(n0 + r0) * ldb + kk;
    const unsigned short* Br1 = Bt + (size_t)(n0 + 64 + r0) * ldb + kk;
    auto stage = [&](int sb, int k0) {
        gload_lds16(Ar0 + k0, (char*)As[sb] + tid * 16);
        gload_lds16(Br0 + k0, (char*)Bs[sb] + tid * 16);
        gload_lds16(Br1 + k0, (char*)Bs[sb] + 4096 + tid * 16);
    };
    const int nk = Kloop >> 5;
    stage(0, 0);
    if (nk > 1) stage(1, 32);
    if (nk > 2) stage(2, 64);
    asm volatile("s_waitcnt vmcnt(6)" ::: "memory");
    __builtin_amdgcn_s_barrier();
    asm volatile("" ::: "memory");
    int buf = 0;
    for (int t = 0; t < nk; ++t) {
        if (t + 3 < nk) stage((buf + 3) & 3, (t + 3) * 32);
        short8 a[4], b[2];
#pragma unroll
        for (int m = 0; m < 4; m++)
            a[m] = *(const short8*)(As[buf] + (m * 16 + l4) * 32 + (g ^ sk) * 8);
#pragma unroll
        for (int n = 0; n < 2; n++)
            b[n] = *(const short8*)(Bs[buf] + (w * 32 + n * 16 + l4) * 32 + (g ^ sk) * 8);
#pragma unroll
        for (int m = 0; m < 4; m++)
#pragma unroll
            for (int n = 0; n < 2; n++)
                acc[m][n] = __builtin_amdgcn_mfma_f32_16x16x32_bf16(a[m], b[n], acc[m][n], 0, 0, 0);
        if (t + 1 < nk) {
            if (t + 3 < nk)      asm volatile("s_waitcnt vmcnt(6)" ::: "memory");
            else if (t + 2 < nk) asm volatile("s_waitcnt vmcnt(3)" ::: "memory");
            else                 asm volatile("s_waitcnt vmcnt(0)" ::: "memory");
            __builtin_amdgcn_s_barrier();
            asm volatile("" ::: "memory");
        }
        buf = (buf + 1) & 3;
    }
    const int rowB = m0 + g * 4;
    const int colB = n0 + w * 32 + l4;
#pragma unroll
    for (int n = 0; n < 2; n++) {
        float bv = bias[colB + n * 16];
#pragma unroll
        for (int m = 0; m < 4; m++) {
#pragma unroll
            for (int r = 0; r < 4; r++) {
                float v = acc[m][n][r] + bv;
                if (EPI == 2) v = fmaxf(v, 0.f);
                size_t idx = (size_t)(rowB + m * 16 + r) * N + colB + n * 16;
                if (EPI == 1) outF[idx] = v;
                else outB[idx] = f2bf(v);
            }
        }
    }
}

// ---------------- flash attention v4: LDS-staged K/V (gload_lds + XOR swizzle) + setprio ----------------
template <int CAUSAL>
__global__ __launch_bounds__(256) void attn4_kernel(const unsigned short* __restrict__ Q, int ldq,
                                                    const unsigned short* __restrict__ Kg, int ldk,
                                                    const unsigned short* __restrict__ Vt,
                                                    unsigned short* __restrict__ O) {
    __shared__ unsigned short Kl[2 * 64 * 64];
    __shared__ unsigned short Vl[2 * 64 * 64];
    __shared__ unsigned short Pl[4][16 * 72];
    const int bh = blockIdx.x, qb = blockIdx.y;
    const int b = bh >> 4, h = bh & 15;
    const int tid = threadIdx.x, w = tid >> 6, lane = tid & 63;
    const int l4 = lane & 15, g = lane >> 4;
    const int q0 = qb * 64 + w * 16;
    const unsigned short* Qp = Q + (size_t)(b * Tc + q0 + l4) * ldq + h * DHc + g * 8;
    short8 qf0 = *(const short8*)Qp;
    short8 qf1 = *(const short8*)(Qp + 32);
    const unsigned short* Kbase = Kg + (size_t)(b * 1024) * ldk + h * DHc;
    const unsigned short* Vbase = Vt + (size_t)bh * DHc * 1024;
    f32x4 o[4] = {};
    float mrun = -1e30f, lrun = 0.f;
    const int nT = CAUSAL ? qb + 1 : 16;
    unsigned short* pw = &Pl[w][l4 * 72];
    const int qi = q0 + l4;

    const int sr0 = tid >> 3;
    const int sr1 = 32 + sr0;
    const int sc_ = (tid & 7) ^ (sr0 & 7);

    auto stage = [&](int s0, int buf) {
        char* kd = (char*)Kl + buf * 8192;
        char* vd = (char*)Vl + buf * 8192;
        gload_lds16(Kbase + (size_t)(s0 + sr0) * ldk + sc_ * 8, kd + tid * 16);
        gload_lds16(Kbase + (size_t)(s0 + sr1) * ldk + sc_ * 8, kd + 4096 + tid * 16);
        gload_lds16(Vbase + (size_t)sr0 * 1024 + s0 + sc_ * 8, vd + tid * 16);
        gload_lds16(Vbase + (size_t)sr1 * 1024 + s0 + sc_ * 8, vd + 4096 + tid * 16);
    };

    stage(0, 0);
    __syncthreads();
    int buf = 0;
    const int sw = l4 & 7;

    for (int t = 0; t < nT; ++t) {
        const int s0 = t * 64;
        if (t + 1 < nT) stage(s0 + 64, buf ^ 1);
        const unsigned short* Kb_ = Kl + buf * 4096;
        const unsigned short* Vb_ = Vl + buf * 4096;
        f32x4 st[4];
        f32x4 z = {0.f, 0.f, 0.f, 0.f};
        __builtin_amdgcn_s_setprio(1);
#pragma unroll
        for (int c = 0; c < 4; c++) {
            const unsigned short* kr = Kb_ + (c * 16 + l4) * 64;
            short8 ka0 = *(const short8*)(kr + ((g ^ sw) * 8));
            short8 ka1 = *(const short8*)(kr + (((g + 4) ^ sw) * 8));
            st[c] = __builtin_amdgcn_mfma_f32_16x16x32_bf16(ka0, qf0, z, 0, 0, 0);
            st[c] = __builtin_amdgcn_mfma_f32_16x16x32_bf16(ka1, qf1, st[c], 0, 0, 0);
        }
        __builtin_amdgcn_s_setprio(0);
        float p[16];
        float tmax = -1e30f;
        const bool domask = CAUSAL && (t == nT - 1);
#pragma unroll
        for (int c = 0; c < 4; c++)
#pragma unroll
            for (int r = 0; r < 4; r++) {
                float v = st[c][r] * 0.125f;
                if (domask && (s0 + c * 16 + g * 4 + r) > qi) v = -1e9f;
                p[c * 4 + r] = v;
                tmax = fmaxf(tmax, v);
            }
        tmax = fmaxf(tmax, __shfl_xor(tmax, 16));
        tmax = fmaxf(tmax, __shfl_xor(tmax, 32));
        if (!__all(tmax <= mrun + 8.f)) {
            float mnew = fmaxf(mrun, tmax);
            float al = __expf(mrun - mnew);
            lrun *= al;
#pragma unroll
            for (int d = 0; d < 4; d++) o[d] *= al;
            mrun = mnew;
        }
        float ps = 0.f;
#pragma unroll
        for (int i = 0; i < 16; i++) { p[i] = __expf(p[i] - mrun); ps += p[i]; }
        ps += __shfl_xor(ps, 16);
        ps += __shfl_xor(ps, 32);
        lrun += ps;
#pragma unroll
        for (int c = 0; c < 4; c++) {
            short4v pk;
            pk[0] = f2bf(p[c * 4 + 0]); pk[1] = f2bf(p[c * 4 + 1]);
            pk[2] = f2bf(p[c * 4 + 2]); pk[3] = f2bf(p[c * 4 + 3]);
            *(short4v*)(pw + c * 16 + g * 4) = pk;
        }
        short8 pb_lo = *(const short8*)(pw + g * 8);
        short8 pb_hi = *(const short8*)(pw + 32 + g * 8);
        __builtin_amdgcn_s_setprio(1);
#pragma unroll
        for (int d = 0; d < 4; d++) {
            const unsigned short* vr = Vb_ + (d * 16 + l4) * 64;
            short8 va0 = *(const short8*)(vr + ((g ^ sw) * 8));
            short8 va1 = *(const short8*)(vr + (((g + 4) ^ sw) * 8));
            o[d] = __builtin_amdgcn_mfma_f32_16x16x32_bf16(va0, pb_lo, o[d], 0, 0, 0);
            o[d] = __builtin_amdgcn_mfma_f32_16x16x32_bf16(va1, pb_hi, o[d], 0, 0, 0);
        }
        __builtin_amdgcn_s_setprio(0);
        __syncthreads();
        buf ^= 1;
    }
    float inv = 1.f / lrun;
    unsigned short* Ob = O + (size_t)(b * Tc + q0 + l4) * Dc + h * DHc;
#pragma unroll
    for (int d = 0; d < 4; d++) {
#pragma unroll
        for (int r = 0; r < 4; r++) Ob[d * 16 + g * 4 + r] = f2bf(o[d][r] * inv);
    }
}

// ---------------- fused residual-add + LayerNorm (bf16 a + bf16 res) ----------------
__global__ __launch_bounds__(256) void ln_bf(const unsigned short* __restrict__ a,
                                             const unsigned short* __restrict__ res,
                                             const float* __restrict__ gam,
                                             const float* __restrict__ bet,
                                             unsigned short* __restrict__ outB,
                                             float* __restrict__ outF) {
    int row = blockIdx.x, t = threadIdx.x;
    size_t base = (size_t)row * Dc + t * 4;
    short4v av = *(const short4v*)(a + base);
    short4v rv = *(const short4v*)(res + base);
    float x0 = bf2f((unsigned short)av[0]) + bf2f((unsigned short)rv[0]);
    float x1 = bf2f((unsigned short)av[1]) + bf2f((unsigned short)rv[1]);
    float x2 = bf2f((unsigned short)av[2]) + bf2f((unsigned short)rv[2]);
    float x3 = bf2f((unsigned short)av[3]) + bf2f((unsigned short)rv[3]);
    float s = x0 + x1 + x2 + x3;
    float ss = x0 * x0 + x1 * x1 + x2 * x2 + x3 * x3;
    for (int o = 1; o < 64; o <<= 1) { s += __shfl_xor(s, o); ss += __shfl_xor(ss, o); }
    __shared__ float S1[4], S2[4];
    int w = t >> 6;
    if ((t & 63) == 0) { S1[w] = s; S2[w] = ss; }
    __syncthreads();
    s = S1[0] + S1[1] + S1[2] + S1[3];
    ss = S2[0] + S2[1] + S2[2] + S2[3];
    float mean = s * (1.f / Dc);
    float var = ss * (1.f / Dc) - mean * mean;
    float rstd = rsqrtf(var + 1e-5f);
    int c = t * 4;
    float4 g4 = *(const float4*)(gam + c);
    float4 b4 = *(const float4*)(bet + c);
    float y0 = (x0 - mean) * rstd * g4.x + b4.x;
    float y1 = (x1 - mean) * rstd * g4.y + b4.y;
    float y2 = (x2 - mean) * rstd * g4.z + b4.z;
    float y3 = (x3 - mean) * rstd * g4.w + b4.w;
    if (outB) {
        short4v ob;
        ob[0] = f2bf(y0); ob[1] = f2bf(y1); ob[2] = f2bf(y2); ob[3] = f2bf(y3);
        *(short4v*)(outB + base) = ob;
    }
    if (outF) { float4 ov = {y0, y1, y2, y3}; *(float4*)(outF + base) = ov; }
}

// ---------------- LN over two f32 split-K partials + bf16 residual ----------------
__global__ __launch_bounds__(256) void ln_2f(const float* __restrict__ a0,
                                             const float* __restrict__ a1,
                                             const unsigned short* __restrict__ res,
                                             const float* __restrict__ gam,
                                             const float* __restrict__ bet,
                                             unsigned short* __restrict__ outB,
                                             float* __restrict__ outF) {
    int row = blockIdx.x, t = threadIdx.x;
    size_t base = (size_t)row * Dc + t * 4;
    float4 u = *(const float4*)(a0 + base);
    float4 v = *(const float4*)(a1 + base);
    short4v rv = *(const short4v*)(res + base);
    float x0 = u.x + v.x + bf2f((unsigned short)rv[0]);
    float x1 = u.y + v.y + bf2f((unsigned short)rv[1]);
    float x2 = u.z + v.z + bf2f((unsigned short)rv[2]);
    float x3 = u.w + v.w + bf2f((unsigned short)rv[3]);
    float s = x0 + x1 + x2 + x3;
    float ss = x0 * x0 + x1 * x1 + x2 * x2 + x3 * x3;
    for (int o = 1; o < 64; o <<= 1) { s += __shfl_xor(s, o); ss += __shfl_xor(ss, o); }
    __shared__ float S1[4], S2[4];
    int w = t >> 6;
    if ((t & 63) == 0) { S1[w] = s; S2[w] = ss; }
    __syncthreads();
    s = S1[0] + S1[1] + S1[2] + S1[3];
    ss = S2[0] + S2[1] + S2[2] + S2[3];
    float mean = s * (1.f / Dc);
    float var = ss * (1.f / Dc) - mean * mean;
    float rstd = rsqrtf(var + 1e-5f);
    int c = t * 4;
    float4 g4 = *(const float4*)(gam + c);
    float4 b4 = *(const float4*)(bet + c);
    float y0 = (x0 - mean) * rstd * g4.x + b4.x;
    float y1 = (x1 - mean) * rstd * g4.y + b4.y;
    float y2 = (x2 - mean) * rstd * g4.z + b4.z;
    float y3 = (x3 - mean) * rstd * g4.w + b4.w;
    if (outB) {
        short4v ob;
        ob[0] = f2bf(y0); ob[1] = f2bf(y1); ob[2] = f2bf(y2); ob[3] = f2bf(y3);
        *(short4v*)(outB + base) = ob;
    }
    if (outF) { float4 ov = {y0, y1, y2, y3}; *(float4*)(outF + base) = ov; }
}

// ---------------- launch ----------------
extern "C" void kernel_launch(void* const* d_in, const int* in_sizes, int n_in,
                              void* d_out, int out_size, void* d_ws, size_t ws_size,
                              hipStream_t stream) {
    const float* x   = (const float*)d_in[0];
    const float* enc = (const float*)d_in[1];
    const float* dWq = (const float*)d_in[4];  const float* dbq = (const float*)d_in[5];
    const float* dWk = (const float*)d_in[6];  const float* dbk = (const float*)d_in[7];
    const float* dWv = (const float*)d_in[8];  const float* dbv = (const float*)d_in[9];
    const float* dWo = (const float*)d_in[10]; const float* dbo = (const float*)d_in[11];
    const float* eWq = (const float*)d_in[12]; const float* ebq = (const float*)d_in[13];
    const float* eWk = (const float*)d_in[14]; const float* ebk = (const float*)d_in[15];
    const float* eWv = (const float*)d_in[16]; const float* ebv = (const float*)d_in[17];
    const float* eWo = (const float*)d_in[18]; const float* ebo = (const float*)d_in[19];
    const float* fW1 = (const float*)d_in[20]; const float* fb1 = (const float*)d_in[21];
    const float* fW2 = (const float*)d_in[22]; const float* fb2 = (const float*)d_in[23];
    const float* g1 = (const float*)d_in[24];  const float* be1 = (const float*)d_in[25];
    const float* g2 = (const float*)d_in[26];  const float* be2 = (const float*)d_in[27];
    const float* g3 = (const float*)d_in[28];  const float* be3 = (const float*)d_in[29];

    char* ws = (char*)d_ws;
    size_t off = 0;
    auto alloc = [&](size_t bytes) -> void* {
        void* p = ws + off;
        off += (bytes + 255) & ~(size_t)255;
        return p;
    };
    const size_t A = (size_t)4096 * 1024;
    const size_t MB1 = (size_t)1024 * 1024;
    char* R1 = (char*)alloc(32 * 1024 * 1024);
    unsigned short* qkv = (unsigned short*)R1;                       // stride 3072
    unsigned short* kvx = (unsigned short*)R1;                       // stride 2048
    unsigned short* qx  = (unsigned short*)(R1 + 16 * 1024 * 1024);  // stride 1024
    unsigned short* h1  = (unsigned short*)R1;                       // 4096x4096
    unsigned short* xb   = (unsigned short*)alloc(A * 2);
    unsigned short* encb = (unsigned short*)alloc(A * 2);
    unsigned short* wqkv = (unsigned short*)alloc(3 * MB1 * 2);
    unsigned short* wekv = (unsigned short*)alloc(2 * MB1 * 2);
    unsigned short* weq  = (unsigned short*)alloc(MB1 * 2);
    unsigned short* wdo  = (unsigned short*)alloc(MB1 * 2);
    unsigned short* weo  = (unsigned short*)alloc(MB1 * 2);
    unsigned short* wf1  = (unsigned short*)alloc(4 * MB1 * 2);
    unsigned short* wf2  = (unsigned short*)alloc(4 * MB1 * 2);
    float* bqkv = (float*)alloc(3072 * 4);
    float* bekv = (float*)alloc(2048 * 4);
    unsigned short* VtB = (unsigned short*)alloc(A * 2);
    unsigned short* ab  = (unsigned short*)alloc(A * 2);
    unsigned short* tmpB = (unsigned short*)alloc(A * 2);
    unsigned short* dB = (unsigned short*)alloc(A * 2);
    unsigned short* fB = (unsigned short*)alloc(A * 2);
    // FFN split-K f32 partials alias the 4x8MB region [VtB, ab, tmpB, dB] (free in FFN phase)
    float* pf0 = (float*)VtB;
    float* pf1 = pf0 + A;
    (void)ws_size; (void)in_sizes; (void)n_in; (void)out_size;

    dim3 tb(32, 8);
    cast_f32_bf16<<<2048, 256, 0, stream>>>(x, xb, (int)(A / 8));
    cast_f32_bf16<<<2048, 256, 0, stream>>>(enc, encb, (int)(A / 8));
    TP8 tp;
    tp.s[0] = dWq; tp.d[0] = wqkv;
    tp.s[1] = dWk; tp.d[1] = wqkv + MB1;
    tp.s[2] = dWv; tp.d[2] = wqkv + 2 * MB1;
    tp.s[3] = eWk; tp.d[3] = wekv;
    tp.s[4] = eWv; tp.d[4] = wekv + MB1;
    tp.s[5] = eWq; tp.d[5] = weq;
    tp.s[6] = dWo; tp.d[6] = wdo;
    tp.s[7] = eWo; tp.d[7] = weo;
    transpose_cast8<<<dim3(32, 32, 8), tb, 0, stream>>>(tp);
    transpose_cast<<<dim3(128, 32), tb, 0, stream>>>(fW1, wf1, 1024, 4096);
    transpose_cast<<<dim3(32, 128), tb, 0, stream>>>(fW2, wf2, 4096, 1024);
    concat_bias<<<12, 256, 0, stream>>>(dbq, dbk, dbv, bqkv);
    concat_bias<<<8, 256, 0, stream>>>(ebk, ebv, ebv, bekv);

    // ---- self-attention block ----
    gemm_db<0><<<dim3(24, 32, 1), 256, 0, stream>>>(xb, wqkv, bqkv, nullptr, qkv, 4096, 3072, 1024, 1024, 1024);
    transpose_v<<<dim3(16, 64), 256, 0, stream>>>(qkv + 2048, 3072, VtB);
    attn4_kernel<1><<<dim3(64, 16), 256, 0, stream>>>(qkv, 3072, qkv + 1024, 3072, VtB, ab);
    gemm64_db<0><<<dim3(8, 64), 256, 0, stream>>>(ab, wdo, dbo, nullptr, tmpB, 4096, 1024, 1024, 1024, 1024);
    ln_bf<<<4096, 256, 0, stream>>>(tmpB, xb, g1, be1, dB, nullptr);

    // ---- cross-attention block ----
    gemm_db<0><<<dim3(16, 32, 1), 256, 0, stream>>>(encb, wekv, bekv, nullptr, kvx, 4096, 2048, 1024, 1024, 1024);
    gemm64_db<0><<<dim3(8, 64), 256, 0, stream>>>(dB, weq, ebq, nullptr, qx, 4096, 1024, 1024, 1024, 1024);
    transpose_v<<<dim3(16, 64), 256, 0, stream>>>(kvx + 1024, 2048, VtB);
    attn4_kernel<0><<<dim3(64, 16), 256, 0, stream>>>(qx, 1024, kvx, 2048, VtB, ab);
    gemm64_db<0><<<dim3(8, 64), 256, 0, stream>>>(ab, weo, ebo, nullptr, tmpB, 4096, 1024, 1024, 1024, 1024);
    ln_bf<<<4096, 256, 0, stream>>>(tmpB, dB, g2, be2, fB, nullptr);

    // ---- FFN block ----
    gemm_db<2><<<dim3(32, 32, 1), 256, 0, stream>>>(fB, wf1, fb1, nullptr, h1, 4096, 4096, 1024, 1024, 1024);
    // FFN2 split-K2 in one dispatch: remapped z selects K-half, f32 partials
    gemm_db<1><<<dim3(8, 32, 2), 256, 0, stream>>>(h1, wf2, fb2, pf0, nullptr, 4096, 1024, 2048, 4096, 4096);
    ln_2f<<<4096, 256, 0, stream>>>(pf0, pf1, fB, g3, be3, nullptr, (float*)d_out);
}

// Round 8
// 363.057 us; speedup vs baseline: 1.0550x; 1.0550x over previous
//
#include <hip/hip_runtime.h>

static constexpr int Bc = 4, Tc = 1024, Sc = 1024, Dc = 1024, Hc = 16, DHc = 64, FFc = 4096;

typedef __attribute__((ext_vector_type(8))) short short8;
typedef __attribute__((ext_vector_type(4))) short short4v;
typedef __attribute__((ext_vector_type(4))) float f32x4;

__device__ __forceinline__ unsigned short f2bf(float f) {
    unsigned int u = __float_as_uint(f);
    unsigned int r = u + 0x7fffu + ((u >> 16) & 1u);
    return (unsigned short)(r >> 16);
}
__device__ __forceinline__ float bf2f(unsigned short u) {
    return __uint_as_float(((unsigned int)u) << 16);
}

__device__ __forceinline__ void gload_lds16(const void* g, void* l) {
    __builtin_amdgcn_global_load_lds((const __attribute__((address_space(1))) void*)g,
                                     (__attribute__((address_space(3))) void*)l, 16, 0, 0);
}

// ---------------- cast f32 -> bf16 ----------------
__global__ __launch_bounds__(256) void cast_f32_bf16(const float* __restrict__ in,
                                                     unsigned short* __restrict__ out, int n8) {
    int i = blockIdx.x * 256 + threadIdx.x;
    if (i >= n8) return;
    const float4* p = (const float4*)in + (size_t)i * 2;
    float4 a = p[0], b = p[1];
    short8 o;
    o[0] = f2bf(a.x); o[1] = f2bf(a.y); o[2] = f2bf(a.z); o[3] = f2bf(a.w);
    o[4] = f2bf(b.x); o[5] = f2bf(b.y); o[6] = f2bf(b.z); o[7] = f2bf(b.w);
    *(short8*)(out + (size_t)i * 8) = o;
}

// ---------------- transpose + cast: W(K,N) f32 -> Wt(N,K) bf16 ----------------
__global__ __launch_bounds__(256) void transpose_cast(const float* __restrict__ W,
                                                      unsigned short* __restrict__ Wt,
                                                      int K, int N) {
    __shared__ float tile[32][33];
    int n0 = blockIdx.x * 32, k0 = blockIdx.y * 32;
    int tx = threadIdx.x, ty = threadIdx.y;  // (32,8)
#pragma unroll
    for (int i = 0; i < 4; i++)
        tile[ty + i * 8][tx] = W[(size_t)(k0 + ty + i * 8) * N + n0 + tx];
    __syncthreads();
#pragma unroll
    for (int i = 0; i < 4; i++)
        Wt[(size_t)(n0 + ty + i * 8) * K + k0 + tx] = f2bf(tile[tx][ty + i * 8]);
}

// batched version for 8 square 1024x1024 weights
struct TP8 { const float* s[8]; unsigned short* d[8]; };
__global__ __launch_bounds__(256) void transpose_cast8(TP8 p) {
    __shared__ float tile[32][33];
    const float* W = p.s[blockIdx.z];
    unsigned short* Wt = p.d[blockIdx.z];
    int n0 = blockIdx.x * 32, k0 = blockIdx.y * 32;
    int tx = threadIdx.x, ty = threadIdx.y;
#pragma unroll
    for (int i = 0; i < 4; i++)
        tile[ty + i * 8][tx] = W[(size_t)(k0 + ty + i * 8) * 1024 + n0 + tx];
    __syncthreads();
#pragma unroll
    for (int i = 0; i < 4; i++)
        Wt[(size_t)(n0 + ty + i * 8) * 1024 + k0 + tx] = f2bf(tile[tx][ty + i * 8]);
}

// ---------------- concat biases (1024-elem segments) ----------------
__global__ void concat_bias(const float* b0, const float* b1, const float* b2,
                            float* __restrict__ out) {
    int i = blockIdx.x * 256 + threadIdx.x;
    int seg = i >> 10, j = i & 1023;
    const float* p = seg == 0 ? b0 : (seg == 1 ? b1 : b2);
    out[i] = p[j];
}

// ---------------- per-head V transpose ----------------
__global__ __launch_bounds__(256) void transpose_v(const unsigned short* __restrict__ V, int ldv,
                                                   unsigned short* __restrict__ Vt) {
    __shared__ unsigned short t[64 * 64];
    const int bh = blockIdx.y, b = bh >> 4, h = bh & 15;
    const int s0 = blockIdx.x * 64;
    const int tid = threadIdx.x;
    const int r = tid >> 2, ch = tid & 3;
    const unsigned short* src = V + (size_t)(b * 1024 + s0 + r) * ldv + h * 64 + ch * 16;
    short8 v0 = *(const short8*)src;
    short8 v1 = *(const short8*)(src + 8);
    int pw_ = (ch ^ r ^ (r >> 4)) & 3;
    *(short8*)(t + r * 64 + pw_ * 16) = v0;
    *(short8*)(t + r * 64 + pw_ * 16 + 8) = v1;
    __syncthreads();
    const int dh = tid >> 2, sc = (tid & 3) * 16;
    short8 o0, o1;
#pragma unroll
    for (int j = 0; j < 8; j++) {
        int c0 = sc + j, c1 = sc + 8 + j;
        o0[j] = t[c0 * 64 + (((dh >> 4) ^ c0 ^ (c0 >> 4)) & 3) * 16 + (dh & 15)];
        o1[j] = t[c1 * 64 + (((dh >> 4) ^ c1 ^ (c1 >> 4)) & 3) * 16 + (dh & 15)];
    }
    unsigned short* dst = Vt + ((size_t)bh * 64 + dh) * 1024 + s0 + sc;
    *(short8*)dst = o0;
    *(short8*)(dst + 8) = o1;
}

// ---- block remap: chunked-XCD + group-major rasterization (bijective, nwg%8==0) ----
struct BlkMap { int m, n, z; };
__device__ __forceinline__ BlkMap remap_block() {
    const int gx = gridDim.x, gy = gridDim.y;
    const int nxy = gx * gy;
    const int nwg = nxy * gridDim.z;
    const int flat = (blockIdx.z * gy + blockIdx.y) * gx + blockIdx.x;
    const int id = (flat & 7) * (nwg >> 3) + (flat >> 3);
    const int pz = id / nxy;
    const int rz = id - pz * nxy;
    const int gwsh = (gx & 7) ? 2 : 3;       // group width 4 if gx%8!=0 (e.g. 12), else 8
    const int gw = 1 << gwsh;
    const int gsz = gw * gy;
    const int grp = rz / gsz;
    const int rem = rz - grp * gsz;
    BlkMap r;
    r.m = rem >> gwsh;
    r.n = (grp << gwsh) + (rem & (gw - 1));
    r.z = pz;
    return r;
}

// ================= GEMM 256x256, BK=64, 8 waves, 4-phase interleave (m201-style) ========
// EPI: 0 = bf16 out, 2 = relu+bf16 out. A(M,K) lda; Bt(N,K) ldb; out row-major stride N.
template <int EPI>
__global__ __launch_bounds__(512, 2) void gemm256(const unsigned short* __restrict__ A,
                                                  const unsigned short* __restrict__ Bt,
                                                  const float* __restrict__ bias,
                                                  unsigned short* __restrict__ outB,
                                                  int N, int lda, int ldb, int nk) {
    __shared__ unsigned short sm[4][16384];  // [0,1]=A dbuf, [2,3]=B dbuf; each 256 rows x 64 bf16
    const int tid = threadIdx.x;
    const int lane = tid & 63, wid = tid >> 6;
    const int l4 = lane & 15, g = lane >> 4;
    const int wr = wid >> 2, wc = wid & 3;   // 2 x 4 wave grid; per-wave out 128x64
    BlkMap bm = remap_block();
    const int m0 = bm.m * 256, n0 = bm.n * 256;
    const int srow = tid >> 3;               // 0..63
    const int schunk = (tid & 7) ^ (srow & 7);
    const int sw = l4 & 7;

    auto stA = [&](int sb, int seg, int k0) {
        gload_lds16(A + (size_t)(m0 + seg * 64 + srow) * lda + k0 + schunk * 8,
                    (char*)sm[sb] + seg * 8192 + tid * 16);
    };
    auto stB = [&](int sb, int seg, int k0) {
        gload_lds16(Bt + (size_t)(n0 + seg * 64 + srow) * ldb + k0 + schunk * 8,
                    (char*)sm[2 + sb] + seg * 8192 + tid * 16);
    };

    f32x4 acc[8][4] = {};
    // prologue: stage tile 0 fully
#pragma unroll
    for (int s = 0; s < 4; s++) stB(0, s, 0);
#pragma unroll
    for (int s = 0; s < 4; s++) stA(0, s, 0);
    asm volatile("s_waitcnt vmcnt(0)" ::: "memory");
    __builtin_amdgcn_s_barrier();

    for (int t = 0; t < nk; ++t) {
        const int bufR = t & 1, bufW = bufR ^ 1;
        const int kn = (t + 1) * 64;
        const bool pf = (t + 1 < nk);
        const unsigned short* As_ = sm[bufR];
        const unsigned short* Bs_ = sm[2 + bufR];
        short8 a[4], b0[4], b1[4];
        // ---- P0: (mh=0, ks=0); stage B seg0,1 of t+1
        if (pf) { stB(bufW, 0, kn); stB(bufW, 1, kn); }
#pragma unroll
        for (int n = 0; n < 4; n++)
            b0[n] = *(const short8*)(Bs_ + (wc * 64 + n * 16 + l4) * 64 + (g ^ sw) * 8);
#pragma unroll
        for (int m = 0; m < 4; m++)
            a[m] = *(const short8*)(As_ + (wr * 128 + m * 16 + l4) * 64 + (g ^ sw) * 8);
        __builtin_amdgcn_s_barrier();
        __builtin_amdgcn_s_setprio(1);
#pragma unroll
        for (int m = 0; m < 4; m++)
#pragma unroll
            for (int n = 0; n < 4; n++)
                acc[m][n] = __builtin_amdgcn_mfma_f32_16x16x32_bf16(a[m], b0[n], acc[m][n], 0, 0, 0);
        __builtin_amdgcn_s_setprio(0);
        __builtin_amdgcn_s_barrier();
        // ---- P1: (mh=0, ks=1); stage B seg2,3
        if (pf) { stB(bufW, 2, kn); stB(bufW, 3, kn); }
#pragma unroll
        for (int n = 0; n < 4; n++)
            b1[n] = *(const short8*)(Bs_ + (wc * 64 + n * 16 + l4) * 64 + ((4 + g) ^ sw) * 8);
#pragma unroll
        for (int m = 0; m < 4; m++)
            a[m] = *(const short8*)(As_ + (wr * 128 + m * 16 + l4) * 64 + ((4 + g) ^ sw) * 8);
        __builtin_amdgcn_s_barrier();
        __builtin_amdgcn_s_setprio(1);
#pragma unroll
        for (int m = 0; m < 4; m++)
#pragma unroll
            for (int n = 0; n < 4; n++)
                acc[m][n] = __builtin_amdgcn_mfma_f32_16x16x32_bf16(a[m], b1[n], acc[m][n], 0, 0, 0);
        __builtin_amdgcn_s_setprio(0);
        // certify A seg1,3 of current tile are resident before P2 reads them
        if (pf) asm volatile("s_waitcnt vmcnt(4)" ::: "memory");
        else    asm volatile("s_waitcnt vmcnt(0)" ::: "memory");
        __builtin_amdgcn_s_barrier();
        // ---- P2: (mh=1, ks=0); stage A seg0,2 (needed first next tile)
        if (pf) { stA(bufW, 0, kn); stA(bufW, 2, kn); }
#pragma unroll
        for (int m = 0; m < 4; m++)
            a[m] = *(const short8*)(As_ + (wr * 128 + 64 + m * 16 + l4) * 64 + (g ^ sw) * 8);
        __builtin_amdgcn_s_barrier();
        __builtin_amdgcn_s_setprio(1);
#pragma unroll
        for (int m = 0; m < 4; m++)
#pragma unroll
            for (int n = 0; n < 4; n++)
                acc[4 + m][n] = __builtin_amdgcn_mfma_f32_16x16x32_bf16(a[m], b0[n], acc[4 + m][n], 0, 0, 0);
        __builtin_amdgcn_s_setprio(0);
        __builtin_amdgcn_s_barrier();
        // ---- P3: (mh=1, ks=1); stage A seg1,3
        if (pf) { stA(bufW, 1, kn); stA(bufW, 3, kn); }
#pragma unroll
        for (int m = 0; m < 4; m++)
            a[m] = *(const short8*)(As_ + (wr * 128 + 64 + m * 16 + l4) * 64 + ((4 + g) ^ sw) * 8);
        __builtin_amdgcn_s_barrier();
        __builtin_amdgcn_s_setprio(1);
#pragma unroll
        for (int m = 0; m < 4; m++)
#pragma unroll
            for (int n = 0; n < 4; n++)
                acc[4 + m][n] = __builtin_amdgcn_mfma_f32_16x16x32_bf16(a[m], b1[n], acc[4 + m][n], 0, 0, 0);
        __builtin_amdgcn_s_setprio(0);
        // certify B0-3 + A0,2 of t+1 (oldest 6 of 8 in flight) before next P0
        if (pf) asm volatile("s_waitcnt vmcnt(2)" ::: "memory");
        __builtin_amdgcn_s_barrier();
    }
    // epilogue
    const int rowB = m0 + wr * 128 + g * 4;
    const int colB = n0 + wc * 64 + l4;
#pragma unroll
    for (int n = 0; n < 4; n++) {
        float bv = bias[colB + n * 16];
#pragma unroll
        for (int m = 0; m < 8; m++) {
#pragma unroll
            for (int r = 0; r < 4; r++) {
                float v = acc[m][n][r] + bv;
                if (EPI == 2) v = fmaxf(v, 0.f);
                outB[(size_t)(rowB + m * 16 + r) * N + colB + n * 16] = f2bf(v);
            }
        }
    }
}

// ---------------- GEMM 128x128: 3-buffer LDS depth-2, counted vmcnt, XCD-swizzled ----------
// EPI: 0 = bf16, 1 = f32 (split-K partial, out += z*M*N, bias only z==0), 2 = relu+bf16
template <int EPI>
__global__ __launch_bounds__(256) void gemm_db(const unsigned short* __restrict__ A,
                                               const unsigned short* __restrict__ Bt,
                                               const float* __restrict__ bias,
                                               float* __restrict__ outF,
                                               unsigned short* __restrict__ outB,
                                               int M, int N, int Kloop, int lda, int ldb) {
    __shared__ unsigned short As[3][128 * 32];
    __shared__ unsigned short Bs[3][128 * 32];
    const int tid = threadIdx.x;
    const int w = tid >> 6, lane = tid & 63, l4 = lane & 15, g = lane >> 4;
    BlkMap bm = remap_block();
    const int m0 = bm.m * 128, n0 = bm.n * 128, z = bm.z;
    A += (size_t)z * Kloop;
    Bt += (size_t)z * Kloop;
    const int wr = w >> 1, wc = w & 1;
    f32x4 acc[4][4] = {};
    const int r0 = tid >> 2;
    const int kk = ((tid & 3) ^ ((tid >> 3) & 3)) * 8;
    const int sk = (l4 >> 1) & 3;
    const unsigned short* Ar0 = A + (size_t)(m0 + r0) * lda + kk;
    const unsigned short* Ar1 = A + (size_t)(m0 + 64 + r0) * lda + kk;
    const unsigned short* Br0 = Bt + (size_t)(n0 + r0) * ldb + kk;
    const unsigned short* Br1 = Bt + (size_t)(n0 + 64 + r0) * ldb + kk;
    auto stage = [&](int sb, int k0) {
        gload_lds16(Ar0 + k0, (char*)As[sb] + tid * 16);
        gload_lds16(Ar1 + k0, (char*)As[sb] + 4096 + tid * 16);
        gload_lds16(Br0 + k0, (char*)Bs[sb] + tid * 16);
        gload_lds16(Br1 + k0, (char*)Bs[sb] + 4096 + tid * 16);
    };
    const int nk = Kloop >> 5;
    stage(0, 0);
    stage(1, 32);
    asm volatile("s_waitcnt vmcnt(4)" ::: "memory");
    __builtin_amdgcn_s_barrier();
    asm volatile("" ::: "memory");
    int buf = 0;
    for (int t = 0; t < nk; ++t) {
        if (t + 2 < nk) {
            int b2 = buf + 2; if (b2 >= 3) b2 -= 3;
            stage(b2, (t + 2) * 32);
        }
        short8 a[4], b[4];
#pragma unroll
        for (int m = 0; m < 4; m++)
            a[m] = *(const short8*)(As[buf] + (wr * 64 + m * 16 + l4) * 32 + (g ^ sk) * 8);
#pragma unroll
        for (int n = 0; n < 4; n++)
            b[n] = *(const short8*)(Bs[buf] + (wc * 64 + n * 16 + l4) * 32 + (g ^ sk) * 8);
#pragma unroll
        for (int m = 0; m < 4; m++)
#pragma unroll
            for (int n = 0; n < 4; n++)
                acc[m][n] = __builtin_amdgcn_mfma_f32_16x16x32_bf16(a[m], b[n], acc[m][n], 0, 0, 0);
        if (t + 1 < nk) {
            if (t + 2 < nk) asm volatile("s_waitcnt vmcnt(4)" ::: "memory");
            else            asm volatile("s_waitcnt vmcnt(0)" ::: "memory");
            __builtin_amdgcn_s_barrier();
            asm volatile("" ::: "memory");
        }
        buf = (buf + 1 == 3) ? 0 : buf + 1;
    }
    const int rowB = m0 + wr * 64 + g * 4;
    const int colB = n0 + wc * 64 + l4;
    float* oF = (EPI == 1) ? outF + (size_t)z * M * N : outF;
#pragma unroll
    for (int n = 0; n < 4; n++) {
        float bv = (EPI == 1 && z != 0) ? 0.f : bias[colB + n * 16];
#pragma unroll
        for (int m = 0; m < 4; m++) {
#pragma unroll
            for (int r = 0; r < 4; r++) {
                float v = acc[m][n][r] + bv;
                if (EPI == 2) v = fmaxf(v, 0.f);
                size_t idx = (size_t)(rowB + m * 16 + r) * N + colB + n * 16;
                if (EPI == 1) oF[idx] = v;
                else outB[idx] = f2bf(v);
            }
        }
    }
}

// ---------------- GEMM 64x128: 3-buffer depth-2, counted vmcnt, XCD-swizzled ----------------
template <int EPI>
__global__ __launch_bounds__(256) void gemm64_db(const unsigned short* __restrict__ A,
                                                 const unsigned short* __restrict__ Bt,
                                                 const float* __restrict__ bias,
                                                 float* __restrict__ outF,
                                                 unsigned short* __restrict__ outB,
                                                 int M, int N, int Kloop, int lda, int ldb) {
    __shared__ unsigned short As[3][64 * 32];
    __shared__ unsigned short Bs[3][128 * 32];
    const int tid = threadIdx.x;
    const int w = tid >> 6, lane = tid & 63, l4 = lane & 15, g = lane >> 4;
    BlkMap bm = remap_block();
    const int m0 = bm.m * 64, n0 = bm.n * 128;
    f32x4 acc[4][2] = {};
    const int r0 = tid >> 2;
    const int kk = ((tid & 3) ^ ((tid >> 3) & 3)) * 8;
    const int sk = (l4 >> 1) & 3;
    const unsigned short* Ar0 = A + (size_t)(m0 + r0) * lda + kk;
    const unsigned short* Br0 = Bt + (size_t)(n0 + r0) * ldb + kk;
    const unsigned short* Br1 = Bt + (size_t)(n0 + 64 + r0) * ldb + kk;
    auto stage = [&](int sb, int k0) {
        gload_lds16(Ar0 + k0, (char*)As[sb] + tid * 16);
        gload_lds16(Br0 + k0, (char*)Bs[sb] + tid * 16);
        gload_lds16(Br1 + k0, (char*)Bs[sb] + 4096 + tid * 16);
    };
    const int nk = Kloop >> 5;
    stage(0, 0);
    stage(1, 32);
    asm volatile("s_waitcnt vmcnt(3)" ::: "memory");
    __builtin_amdgcn_s_barrier();
    asm volatile("" ::: "memory");
    int buf = 0;
    for (int t = 0; t < nk; ++t) {
        if (t + 2 < nk) {
            int b2 = buf + 2; if (b2 >= 3) b2 -= 3;
            stage(b2, (t + 2) * 32);
        }
        short8 a[4], b[2];
#pragma unroll
        for (int m = 0; m < 4; m++)
            a[m] = *(const short8*)(As[buf] + (m * 16 + l4) * 32 + (g ^ sk) * 8);
#pragma unroll
        for (int n = 0; n < 2; n++)
            b[n] = *(const short8*)(Bs[buf] + (w * 32 + n * 16 + l4) * 32 + (g ^ sk) * 8);
#pragma unroll
        for (int m = 0; m < 4; m++)
#pragma unroll
            for (int n = 0; n < 2; n++)
                acc[m][n] = __builtin_amdgcn_mfma_f32_16x16x32_bf16(a[m], b[n], acc[m][n], 0, 0, 0);
        if (t + 1 < nk) {
            if (t + 2 < nk) asm volatile("s_waitcnt vmcnt(3)" ::: "memory");
            else            asm volatile("s_waitcnt vmcnt(0)" ::: "memory");
            __builtin_amdgcn_s_barrier();
            asm volatile("" ::: "memory");
        }
        buf = (buf + 1 == 3) ? 0 : buf + 1;
    }
    const int rowB = m0 + g * 4;
    const int colB = n0 + w * 32 + l4;
#pragma unroll
    for (int n = 0; n < 2; n++) {
        float bv = bias[colB + n * 16];
#pragma unroll
        for (int m = 0; m < 4; m++) {
#pragma unroll
            for (int r = 0; r < 4; r++) {
                float v = acc[m][n][r] + bv;
                if (EPI == 2) v = fmaxf(v, 0.f);
                size_t idx = (size_t)(rowB + m * 16 + r) * N + colB + n * 16;
                if (EPI == 1) outF[idx] = v;
                else outB[idx] = f2bf(v);
            }
        }
    }
}

// ---------------- flash attention v4: LDS-staged K/V (gload_lds + XOR swizzle) + setprio ----------------
template <int CAUSAL>
__global__ __launch_bounds__(256) void attn4_kernel(const unsigned short* __restrict__ Q, int ldq,
                                                    const unsigned short* __restrict__ Kg, int ldk,
                                                    const unsigned short* __restrict__ Vt,
                                                    unsigned short* __restrict__ O) {
    __shared__ unsigned short Kl[2 * 64 * 64];
    __shared__ unsigned short Vl[2 * 64 * 64];
    __shared__ unsigned short Pl[4][16 * 72];
    const int bh = blockIdx.x, qb = blockIdx.y;
    const int b = bh >> 4, h = bh & 15;
    const int tid = threadIdx.x, w = tid >> 6, lane = tid & 63;
    const int l4 = lane & 15, g = lane >> 4;
    const int q0 = qb * 64 + w * 16;
    const unsigned short* Qp = Q + (size_t)(b * Tc + q0 + l4) * ldq + h * DHc + g * 8;
    short8 qf0 = *(const short8*)Qp;
    short8 qf1 = *(const short8*)(Qp + 32);
    const unsigned short* Kbase = Kg + (size_t)(b * 1024) * ldk + h * DHc;
    const unsigned short* Vbase = Vt + (size_t)bh * DHc * 1024;
    f32x4 o[4] = {};
    float mrun = -1e30f, lrun = 0.f;
    const int nT = CAUSAL ? qb + 1 : 16;
    unsigned short* pw = &Pl[w][l4 * 72];
    const int qi = q0 + l4;

    const int sr0 = tid >> 3;
    const int sr1 = 32 + sr0;
    const int sc_ = (tid & 7) ^ (sr0 & 7);

    auto stage = [&](int s0, int buf) {
        char* kd = (char*)Kl + buf * 8192;
        char* vd = (char*)Vl + buf * 8192;
        gload_lds16(Kbase + (size_t)(s0 + sr0) * ldk + sc_ * 8, kd + tid * 16);
        gload_lds16(Kbase + (size_t)(s0 + sr1) * ldk + sc_ * 8, kd + 4096 + tid * 16);
        gload_lds16(Vbase + (size_t)sr0 * 1024 + s0 + sc_ * 8, vd + tid * 16);
        gload_lds16(Vbase + (size_t)sr1 * 1024 + s0 + sc_ * 8, vd + 4096 + tid * 16);
    };

    stage(0, 0);
    __syncthreads();
    int buf = 0;
    const int sw = l4 & 7;

    for (int t = 0; t < nT; ++t) {
        const int s0 = t * 64;
        if (t + 1 < nT) stage(s0 + 64, buf ^ 1);
        const unsigned short* Kb_ = Kl + buf * 4096;
        const unsigned short* Vb_ = Vl + buf * 4096;
        f32x4 st[4];
        f32x4 z = {0.f, 0.f, 0.f, 0.f};
        __builtin_amdgcn_s_setprio(1);
#pragma unroll
        for (int c = 0; c < 4; c++) {
            const unsigned short* kr = Kb_ + (c * 16 + l4) * 64;
            short8 ka0 = *(const short8*)(kr + ((g ^ sw) * 8));
            short8 ka1 = *(const short8*)(kr + (((g + 4) ^ sw) * 8));
            st[c] = __builtin_amdgcn_mfma_f32_16x16x32_bf16(ka0, qf0, z, 0, 0, 0);
            st[c] = __builtin_amdgcn_mfma_f32_16x16x32_bf16(ka1, qf1, st[c], 0, 0, 0);
        }
        __builtin_amdgcn_s_setprio(0);
        float p[16];
        float tmax = -1e30f;
        const bool domask = CAUSAL && (t == nT - 1);
#pragma unroll
        for (int c = 0; c < 4; c++)
#pragma unroll
            for (int r = 0; r < 4; r++) {
                float v = st[c][r] * 0.125f;
                if (domask && (s0 + c * 16 + g * 4 + r) > qi) v = -1e9f;
                p[c * 4 + r] = v;
                tmax = fmaxf(tmax, v);
            }
        tmax = fmaxf(tmax, __shfl_xor(tmax, 16));
        tmax = fmaxf(tmax, __shfl_xor(tmax, 32));
        if (!__all(tmax <= mrun + 8.f)) {
            float mnew = fmaxf(mrun, tmax);
            float al = __expf(mrun - mnew);
            lrun *= al;
#pragma unroll
            for (int d = 0; d < 4; d++) o[d] *= al;
            mrun = mnew;
        }
        float ps = 0.f;
#pragma unroll
        for (int i = 0; i < 16; i++) { p[i] = __expf(p[i] - mrun); ps += p[i]; }
        ps += __shfl_xor(ps, 16);
        ps += __shfl_xor(ps, 32);
        lrun += ps;
#pragma unroll
        for (int c = 0; c < 4; c++) {
            short4v pk;
            pk[0] = f2bf(p[c * 4 + 0]); pk[1] = f2bf(p[c * 4 + 1]);
            pk[2] = f2bf(p[c * 4 + 2]); pk[3] = f2bf(p[c * 4 + 3]);
            *(short4v*)(pw + c * 16 + g * 4) = pk;
        }
        short8 pb_lo = *(const short8*)(pw + g * 8);
        short8 pb_hi = *(const short8*)(pw + 32 + g * 8);
        __builtin_amdgcn_s_setprio(1);
#pragma unroll
        for (int d = 0; d < 4; d++) {
            const unsigned short* vr = Vb_ + (d * 16 + l4) * 64;
            short8 va0 = *(const short8*)(vr + ((g ^ sw) * 8));
            short8 va1 = *(const short8*)(vr + (((g + 4) ^ sw) * 8));
            o[d] = __builtin_amdgcn_mfma_f32_16x16x32_bf16(va0, pb_lo, o[d], 0, 0, 0);
            o[d] = __builtin_amdgcn_mfma_f32_16x16x32_bf16(va1, pb_hi, o[d], 0, 0, 0);
        }
        __builtin_amdgcn_s_setprio(0);
        __syncthreads();
        buf ^= 1;
    }
    float inv = 1.f / lrun;
    unsigned short* Ob = O + (size_t)(b * Tc + q0 + l4) * Dc + h * DHc;
#pragma unroll
    for (int d = 0; d < 4; d++) {
#pragma unroll
        for (int r = 0; r < 4; r++) Ob[d * 16 + g * 4 + r] = f2bf(o[d][r] * inv);
    }
}

// ---------------- fused residual-add + LayerNorm (bf16 a + bf16 res) ----------------
__global__ __launch_bounds__(256) void ln_bf(const unsigned short* __restrict__ a,
                                             const unsigned short* __restrict__ res,
                                             const float* __restrict__ gam,
                                             const float* __restrict__ bet,
                                             unsigned short* __restrict__ outB,
                                             float* __restrict__ outF) {
    int row = blockIdx.x, t = threadIdx.x;
    size_t base = (size_t)row * Dc + t * 4;
    short4v av = *(const short4v*)(a + base);
    short4v rv = *(const short4v*)(res + base);
    float x0 = bf2f((unsigned short)av[0]) + bf2f((unsigned short)rv[0]);
    float x1 = bf2f((unsigned short)av[1]) + bf2f((unsigned short)rv[1]);
    float x2 = bf2f((unsigned short)av[2]) + bf2f((unsigned short)rv[2]);
    float x3 = bf2f((unsigned short)av[3]) + bf2f((unsigned short)rv[3]);
    float s = x0 + x1 + x2 + x3;
    float ss = x0 * x0 + x1 * x1 + x2 * x2 + x3 * x3;
    for (int o = 1; o < 64; o <<= 1) { s += __shfl_xor(s, o); ss += __shfl_xor(ss, o); }
    __shared__ float S1[4], S2[4];
    int w = t >> 6;
    if ((t & 63) == 0) { S1[w] = s; S2[w] = ss; }
    __syncthreads();
    s = S1[0] + S1[1] + S1[2] + S1[3];
    ss = S2[0] + S2[1] + S2[2] + S2[3];
    float mean = s * (1.f / Dc);
    float var = ss * (1.f / Dc) - mean * mean;
    float rstd = rsqrtf(var + 1e-5f);
    int c = t * 4;
    float4 g4 = *(const float4*)(gam + c);
    float4 b4 = *(const float4*)(bet + c);
    float y0 = (x0 - mean) * rstd * g4.x + b4.x;
    float y1 = (x1 - mean) * rstd * g4.y + b4.y;
    float y2 = (x2 - mean) * rstd * g4.z + b4.z;
    float y3 = (x3 - mean) * rstd * g4.w + b4.w;
    if (outB) {
        short4v ob;
        ob[0] = f2bf(y0); ob[1] = f2bf(y1); ob[2] = f2bf(y2); ob[3] = f2bf(y3);
        *(short4v*)(outB + base) = ob;
    }
    if (outF) { float4 ov = {y0, y1, y2, y3}; *(float4*)(outF + base) = ov; }
}

// ---------------- LN over two f32 split-K partials + bf16 residual ----------------
__global__ __launch_bounds__(256) void ln_2f(const float* __restrict__ a0,
                                             const float* __restrict__ a1,
                                             const unsigned short* __restrict__ res,
                                             const float* __restrict__ gam,
                                             const float* __restrict__ bet,
                                             unsigned short* __restrict__ outB,
                                             float* __restrict__ outF) {
    int row = blockIdx.x, t = threadIdx.x;
    size_t base = (size_t)row * Dc + t * 4;
    float4 u = *(const float4*)(a0 + base);
    float4 v = *(const float4*)(a1 + base);
    short4v rv = *(const short4v*)(res + base);
    float x0 = u.x + v.x + bf2f((unsigned short)rv[0]);
    float x1 = u.y + v.y + bf2f((unsigned short)rv[1]);
    float x2 = u.z + v.z + bf2f((unsigned short)rv[2]);
    float x3 = u.w + v.w + bf2f((unsigned short)rv[3]);
    float s = x0 + x1 + x2 + x3;
    float ss = x0 * x0 + x1 * x1 + x2 * x2 + x3 * x3;
    for (int o = 1; o < 64; o <<= 1) { s += __shfl_xor(s, o); ss += __shfl_xor(ss, o); }
    __shared__ float S1[4], S2[4];
    int w = t >> 6;
    if ((t & 63) == 0) { S1[w] = s; S2[w] = ss; }
    __syncthreads();
    s = S1[0] + S1[1] + S1[2] + S1[3];
    ss = S2[0] + S2[1] + S2[2] + S2[3];
    float mean = s * (1.f / Dc);
    float var = ss * (1.f / Dc) - mean * mean;
    float rstd = rsqrtf(var + 1e-5f);
    int c = t * 4;
    float4 g4 = *(const float4*)(gam + c);
    float4 b4 = *(const float4*)(bet + c);
    float y0 = (x0 - mean) * rstd * g4.x + b4.x;
    float y1 = (x1 - mean) * rstd * g4.y + b4.y;
    float y2 = (x2 - mean) * rstd * g4.z + b4.z;
    float y3 = (x3 - mean) * rstd * g4.w + b4.w;
    if (outB) {
        short4v ob;
        ob[0] = f2bf(y0); ob[1] = f2bf(y1); ob[2] = f2bf(y2); ob[3] = f2bf(y3);
        *(short4v*)(outB + base) = ob;
    }
    if (outF) { float4 ov = {y0, y1, y2, y3}; *(float4*)(outF + base) = ov; }
}

// ---------------- launch ----------------
extern "C" void kernel_launch(void* const* d_in, const int* in_sizes, int n_in,
                              void* d_out, int out_size, void* d_ws, size_t ws_size,
                              hipStream_t stream) {
    const float* x   = (const float*)d_in[0];
    const float* enc = (const float*)d_in[1];
    const float* dWq = (const float*)d_in[4];  const float* dbq = (const float*)d_in[5];
    const float* dWk = (const float*)d_in[6];  const float* dbk = (const float*)d_in[7];
    const float* dWv = (const float*)d_in[8];  const float* dbv = (const float*)d_in[9];
    const float* dWo = (const float*)d_in[10]; const float* dbo = (const float*)d_in[11];
    const float* eWq = (const float*)d_in[12]; const float* ebq = (const float*)d_in[13];
    const float* eWk = (const float*)d_in[14]; const float* ebk = (const float*)d_in[15];
    const float* eWv = (const float*)d_in[16]; const float* ebv = (const float*)d_in[17];
    const float* eWo = (const float*)d_in[18]; const float* ebo = (const float*)d_in[19];
    const float* fW1 = (const float*)d_in[20]; const float* fb1 = (const float*)d_in[21];
    const float* fW2 = (const float*)d_in[22]; const float* fb2 = (const float*)d_in[23];
    const float* g1 = (const float*)d_in[24];  const float* be1 = (const float*)d_in[25];
    const float* g2 = (const float*)d_in[26];  const float* be2 = (const float*)d_in[27];
    const float* g3 = (const float*)d_in[28];  const float* be3 = (const float*)d_in[29];

    char* ws = (char*)d_ws;
    size_t off = 0;
    auto alloc = [&](size_t bytes) -> void* {
        void* p = ws + off;
        off += (bytes + 255) & ~(size_t)255;
        return p;
    };
    const size_t A = (size_t)4096 * 1024;
    const size_t MB1 = (size_t)1024 * 1024;
    char* R1 = (char*)alloc(32 * 1024 * 1024);
    unsigned short* qkv = (unsigned short*)R1;                       // stride 3072
    unsigned short* kvx = (unsigned short*)R1;                       // stride 2048
    unsigned short* qx  = (unsigned short*)(R1 + 16 * 1024 * 1024);  // stride 1024
    unsigned short* h1  = (unsigned short*)R1;                       // 4096x4096
    unsigned short* xb   = (unsigned short*)alloc(A * 2);
    unsigned short* encb = (unsigned short*)alloc(A * 2);
    unsigned short* wqkv = (unsigned short*)alloc(3 * MB1 * 2);
    unsigned short* wekv = (unsigned short*)alloc(2 * MB1 * 2);
    unsigned short* weq  = (unsigned short*)alloc(MB1 * 2);
    unsigned short* wdo  = (unsigned short*)alloc(MB1 * 2);
    unsigned short* weo  = (unsigned short*)alloc(MB1 * 2);
    unsigned short* wf1  = (unsigned short*)alloc(4 * MB1 * 2);
    unsigned short* wf2  = (unsigned short*)alloc(4 * MB1 * 2);
    float* bqkv = (float*)alloc(3072 * 4);
    float* bekv = (float*)alloc(2048 * 4);
    unsigned short* VtB = (unsigned short*)alloc(A * 2);
    unsigned short* ab  = (unsigned short*)alloc(A * 2);
    unsigned short* tmpB = (unsigned short*)alloc(A * 2);
    unsigned short* dB = (unsigned short*)alloc(A * 2);
    unsigned short* fB = (unsigned short*)alloc(A * 2);
    float* pf0 = (float*)VtB;
    float* pf1 = pf0 + A;
    (void)ws_size; (void)in_sizes; (void)n_in; (void)out_size;

    dim3 tb(32, 8);
    cast_f32_bf16<<<2048, 256, 0, stream>>>(x, xb, (int)(A / 8));
    cast_f32_bf16<<<2048, 256, 0, stream>>>(enc, encb, (int)(A / 8));
    TP8 tp;
    tp.s[0] = dWq; tp.d[0] = wqkv;
    tp.s[1] = dWk; tp.d[1] = wqkv + MB1;
    tp.s[2] = dWv; tp.d[2] = wqkv + 2 * MB1;
    tp.s[3] = eWk; tp.d[3] = wekv;
    tp.s[4] = eWv; tp.d[4] = wekv + MB1;
    tp.s[5] = eWq; tp.d[5] = weq;
    tp.s[6] = dWo; tp.d[6] = wdo;
    tp.s[7] = eWo; tp.d[7] = weo;
    transpose_cast8<<<dim3(32, 32, 8), tb, 0, stream>>>(tp);
    transpose_cast<<<dim3(128, 32), tb, 0, stream>>>(fW1, wf1, 1024, 4096);
    transpose_cast<<<dim3(32, 128), tb, 0, stream>>>(fW2, wf2, 4096, 1024);
    concat_bias<<<12, 256, 0, stream>>>(dbq, dbk, dbv, bqkv);
    concat_bias<<<8, 256, 0, stream>>>(ebk, ebv, ebv, bekv);

    // ---- self-attention block ----
    gemm256<0><<<dim3(12, 16), 512, 0, stream>>>(xb, wqkv, bqkv, qkv, 3072, 1024, 1024, 16);
    transpose_v<<<dim3(16, 64), 256, 0, stream>>>(qkv + 2048, 3072, VtB);
    attn4_kernel<1><<<dim3(64, 16), 256, 0, stream>>>(qkv, 3072, qkv + 1024, 3072, VtB, ab);
    gemm64_db<0><<<dim3(8, 64), 256, 0, stream>>>(ab, wdo, dbo, nullptr, tmpB, 4096, 1024, 1024, 1024, 1024);
    ln_bf<<<4096, 256, 0, stream>>>(tmpB, xb, g1, be1, dB, nullptr);

    // ---- cross-attention block ----
    gemm_db<0><<<dim3(16, 32, 1), 256, 0, stream>>>(encb, wekv, bekv, nullptr, kvx, 4096, 2048, 1024, 1024, 1024);
    gemm64_db<0><<<dim3(8, 64), 256, 0, stream>>>(dB, weq, ebq, nullptr, qx, 4096, 1024, 1024, 1024, 1024);
    transpose_v<<<dim3(16, 64), 256, 0, stream>>>(kvx + 1024, 2048, VtB);
    attn4_kernel<0><<<dim3(64, 16), 256, 0, stream>>>(qx, 1024, kvx, 2048, VtB, ab);
    gemm64_db<0><<<dim3(8, 64), 256, 0, stream>>>(ab, weo, ebo, nullptr, tmpB, 4096, 1024, 1024, 1024, 1024);
    ln_bf<<<4096, 256, 0, stream>>>(tmpB, dB, g2, be2, fB, nullptr);

    // ---- FFN block ----
    gemm256<2><<<dim3(16, 16), 512, 0, stream>>>(fB, wf1, fb1, h1, 4096, 1024, 1024, 16);
    gemm_db<1><<<dim3(8, 32, 2), 256, 0, stream>>>(h1, wf2, fb2, pf0, nullptr, 4096, 1024, 2048, 4096, 4096);
    ln_2f<<<4096, 256, 0, stream>>>(pf0, pf1, fB, g3, be3, nullptr, (float*)d_out);
}